// Round 1
// baseline (209.982 us; speedup 1.0000x reference)
//
#include <hip/hip_runtime.h>

#define NTOT 8192
#define NU 4096
#define D 64
#define MAXN 128

__device__ __forceinline__ float wave_sum(float x){
  #pragma unroll
  for(int off=32;off;off>>=1) x += __shfl_xor(x,off);
  return x;
}
__device__ __forceinline__ float wave_max(float x){
  #pragma unroll
  for(int off=32;off;off>>=1) x = fmaxf(x,__shfl_xor(x,off));
  return x;
}

// ---- K1: build padded ELL adjacency (one wave per row) ----
__global__ __launch_bounds__(256) void build_ell(const float* __restrict__ adj,
                                                 int* __restrict__ ell,
                                                 int* __restrict__ nnz){
  int lane = threadIdx.x & 63;
  int row  = blockIdx.x * 4 + (threadIdx.x >> 6);
  const float4* arow = (const float4*)(adj + (size_t)row * NTOT);
  int base = 0;
  for(int c0 = 0; c0 < NTOT/4; c0 += 64){
    float4 v = arow[c0 + lane];
    #pragma unroll
    for(int j = 0; j < 4; ++j){
      float f = (j==0)?v.x:(j==1)?v.y:(j==2)?v.z:v.w;
      unsigned long long m = __ballot(f != 0.0f);
      if(f != 0.0f){
        int slot = base + __popcll(m & ((1ull<<lane)-1ull));
        if(slot < MAXN) ell[row*MAXN + slot] = (c0 + lane)*4 + j;
      }
      base += __popcll(m);
    }
  }
  if(lane == 0) nnz[row] = base > MAXN ? MAXN : base;
}

// ---- K0: concat embeddings ----
__global__ void concat_emb(const float* __restrict__ ut, const float* __restrict__ it,
                           float* __restrict__ all_emb){
  int i = blockIdx.x * 256 + threadIdx.x;           // 524288 total
  all_emb[i] = (i < NU*D) ? ut[i] : it[i - NU*D];
}

// ---- K2: GCN layer: y = relu((nbr-sum x) @ W + b), one wave per row ----
__global__ __launch_bounds__(256) void gcn_layer(const float* __restrict__ x,
    const int* __restrict__ ell, const int* __restrict__ nnz,
    const float* __restrict__ W, const float* __restrict__ b,
    float* __restrict__ y){
  __shared__ float Ws[D*D];
  __shared__ float bs[D];
  for(int i = threadIdx.x; i < D*D; i += 256) Ws[i] = W[i];
  if(threadIdx.x < D) bs[threadIdx.x] = b[threadIdx.x];
  __syncthreads();
  int lane = threadIdx.x & 63;
  int row  = blockIdx.x * 4 + (threadIdx.x >> 6);
  int cnt  = nnz[row];
  const int* cols = ell + row*MAXN;
  float acc = 0.f;
  for(int t = 0; t < cnt; ++t){
    int j = cols[t];
    acc += x[j*D + lane];
  }
  float yd = bs[lane];
  #pragma unroll 8
  for(int k = 0; k < D; ++k) yd += __shfl(acc, k) * Ws[k*D + lane];
  y[row*D + lane] = fmaxf(yd, 0.f);
}

// ---- K3: GAT h = x@W + b, plus q = h@a1, k = h@a2 ----
__global__ __launch_bounds__(256) void gat_h(const float* __restrict__ x,
    const float* __restrict__ W, const float* __restrict__ b,
    const float* __restrict__ aW,
    float* __restrict__ h, float* __restrict__ qv, float* __restrict__ kvv){
  __shared__ float Ws[D*D];
  __shared__ float bs[D], a1s[D], a2s[D];
  for(int i = threadIdx.x; i < D*D; i += 256) Ws[i] = W[i];
  if(threadIdx.x < D){
    bs[threadIdx.x]  = b[threadIdx.x];
    a1s[threadIdx.x] = aW[threadIdx.x];
    a2s[threadIdx.x] = aW[D + threadIdx.x];
  }
  __syncthreads();
  int lane = threadIdx.x & 63;
  int row  = blockIdx.x * 4 + (threadIdx.x >> 6);
  float xd = x[row*D + lane];
  float hd = bs[lane];
  #pragma unroll 8
  for(int k = 0; k < D; ++k) hd += __shfl(xd, k) * Ws[k*D + lane];
  h[row*D + lane] = hd;
  float q  = wave_sum(hd * a1s[lane]);
  float kk = wave_sum(hd * a2s[lane]);
  if(lane == 0){ qv[row] = q; kvv[row] = kk; }
}

// ---- K4: column sum S = sum_rows h (two-step, deterministic) ----
__global__ void colsum_part(const float* __restrict__ h, float* __restrict__ part){
  int d = threadIdx.x;            // 64 threads
  int b = blockIdx.x;             // 256 blocks, 32 rows each
  float s = 0.f;
  for(int r = b*32; r < b*32 + 32; ++r) s += h[r*D + d];
  part[b*D + d] = s;
}
__global__ void colsum_final(const float* __restrict__ part, float* __restrict__ S){
  int d = threadIdx.x;
  float s = 0.f;
  for(int b = 0; b < 256; ++b) s += part[b*D + d];
  S[d] = s;
}

// ---- K5: GAT attention aggregate (analytic softmax over e*adj) ----
__global__ __launch_bounds__(256) void gat_attn(const float* __restrict__ h,
    const float* __restrict__ qv, const float* __restrict__ kvv,
    const int* __restrict__ ell, const int* __restrict__ nnz,
    const float* __restrict__ S, const float* __restrict__ attn_b_p,
    float* __restrict__ out){
  int lane = threadIdx.x & 63;
  int row  = blockIdx.x * 4 + (threadIdx.x >> 6);
  int cnt  = nnz[row];
  float q  = qv[row];
  float ab = attn_b_p[0];
  const int* cols = ell + row*MAXN;
  // pass A: running max m (includes the 0 from non-edges)
  float m = 0.f;
  for(int t0 = 0; t0 < cnt; t0 += 64){
    int t = t0 + lane;
    float e = -1e30f;
    if(t < cnt){
      float x = q + kvv[cols[t]] + ab;
      e = (x >= 0.f) ? x : 0.01f * x;
    }
    m = fmaxf(m, wave_max(e));
  }
  float em = expf(-m);
  float Z  = (float)(NTOT - cnt) * em;
  float accd = 0.f, hsumd = 0.f;
  for(int t0 = 0; t0 < cnt; t0 += 64){
    int t = t0 + lane;
    float w = 0.f; int col = 0;
    if(t < cnt){
      col = cols[t];
      float x = q + kvv[col] + ab;
      float e = (x >= 0.f) ? x : 0.01f * x;
      w = expf(e - m);
    }
    Z += wave_sum(w);
    int lim = (cnt - t0 < 64) ? (cnt - t0) : 64;
    for(int tt = 0; tt < lim; ++tt){
      float wt = __shfl(w, tt);
      int  j   = __shfl(col, tt);
      float hv = h[j*D + lane];
      accd  += wt * hv;
      hsumd += hv;
    }
  }
  float outd = (accd + em * (S[lane] - hsumd)) / Z;
  out[row*D + lane] = fmaxf(outd, 0.f);
}

// ---- K6: fuse both layers ----
__global__ __launch_bounds__(256) void fuse_kernel(const float* __restrict__ gcn1,
    const float* __restrict__ gat1, const float* __restrict__ gcn2, const float* __restrict__ gat2,
    const float* __restrict__ fuse_W, const float* __restrict__ fuse_b,
    const float* __restrict__ layer_w, float* __restrict__ fused){
  __shared__ float Wf[2*D*D];     // 32 KB, staged per layer
  __shared__ float bf_[D];
  int lane = threadIdx.x & 63;
  int row  = blockIdx.x * 4 + (threadIdx.x >> 6);
  float l0 = layer_w[0], l1 = layer_w[1];
  float mx = fmaxf(l0, l1);
  float e0 = expf(l0-mx), e1 = expf(l1-mx);
  float inv = 1.f/(e0+e1);
  float lw0 = e0*inv, lw1 = e1*inv;

  // layer 0
  for(int i = threadIdx.x; i < 2*D*D; i += 256) Wf[i] = fuse_W[i];
  if(threadIdx.x < D) bf_[threadIdx.x] = fuse_b[threadIdx.x];
  __syncthreads();
  float g = gcn1[row*D + lane], a = gat1[row*D + lane];
  float y0 = bf_[lane];
  #pragma unroll 8
  for(int k = 0; k < D; ++k){
    y0 += __shfl(g, k) * Wf[k*D + lane];
    y0 += __shfl(a, k) * Wf[(D+k)*D + lane];
  }
  __syncthreads();
  // layer 1
  for(int i = threadIdx.x; i < 2*D*D; i += 256) Wf[i] = fuse_W[2*D*D + i];
  if(threadIdx.x < D) bf_[threadIdx.x] = fuse_b[D + threadIdx.x];
  __syncthreads();
  g = gcn2[row*D + lane]; a = gat2[row*D + lane];
  float y1 = bf_[lane];
  #pragma unroll 8
  for(int k = 0; k < D; ++k){
    y1 += __shfl(g, k) * Wf[k*D + lane];
    y1 += __shfl(a, k) * Wf[(D+k)*D + lane];
  }
  fused[row*D + lane] = lw0*fmaxf(y0,0.f) + lw1*fmaxf(y1,0.f);
}

// ---- K7: scoring + critic ----
__global__ __launch_bounds__(256) void score_kernel(const float* __restrict__ fused,
    const int* __restrict__ users, const int* __restrict__ pos, const int* __restrict__ neg,
    const float* __restrict__ AW, const float* __restrict__ abias,
    const float* __restrict__ cW1, const float* __restrict__ cb1,
    const float* __restrict__ cW2, const float* __restrict__ cb2,
    float* __restrict__ out){
  __shared__ float AWs[D*D];      // 16 KB
  __shared__ float C1s[2*D*D];    // 32 KB
  __shared__ float abs_[D], cb1s[D], C2s[D];
  for(int i = threadIdx.x; i < D*D; i += 256) AWs[i] = AW[i];
  for(int i = threadIdx.x; i < 2*D*D; i += 256) C1s[i] = cW1[i];
  if(threadIdx.x < D){
    abs_[threadIdx.x] = abias[threadIdx.x];
    cb1s[threadIdx.x] = cb1[threadIdx.x];
    C2s[threadIdx.x]  = cW2[threadIdx.x];
  }
  __syncthreads();
  int lane = threadIdx.x & 63;
  int bi   = blockIdx.x * 4 + (threadIdx.x >> 6);
  int ui = users[bi], pi = pos[bi] + NU, ni = neg[bi] + NU;
  float ud = fused[ui*D + lane], pd = fused[pi*D + lane], nd = fused[ni*D + lane];
  float ufd = abs_[lane];
  #pragma unroll 8
  for(int k = 0; k < D; ++k) ufd += __shfl(ud, k) * AWs[k*D + lane];
  float ps = wave_sum(ufd * pd);
  float ns = wave_sum(ufd * nd);
  float hu = cb1s[lane];
  #pragma unroll 8
  for(int k = 0; k < D; ++k) hu += __shfl(ud, k) * C1s[k*D + lane];
  float hp = hu, hn = hu;
  #pragma unroll 8
  for(int k = 0; k < D; ++k){
    float pk = __shfl(pd, k), nk = __shfl(nd, k);
    hp += pk * C1s[(D+k)*D + lane];
    hn += nk * C1s[(D+k)*D + lane];
  }
  hp = fmaxf(hp, 0.f); hn = fmaxf(hn, 0.f);
  float cp = wave_sum(hp * C2s[lane]);
  float cn = wave_sum(hn * C2s[lane]);
  if(lane == 0){
    out[bi]          = ps;
    out[4096  + bi]  = ns;
    out[8192  + bi]  = cp + cb2[0];
    out[12288 + bi]  = cn + cb2[0];
  }
}

extern "C" void kernel_launch(void* const* d_in, const int* in_sizes, int n_in,
                              void* d_out, int out_size, void* d_ws, size_t ws_size,
                              hipStream_t stream){
  const float* adj        = (const float*)d_in[0];
  const int*   users      = (const int*)d_in[1];
  const int*   pos        = (const int*)d_in[2];
  const int*   neg        = (const int*)d_in[3];
  const float* user_table = (const float*)d_in[4];
  const float* item_table = (const float*)d_in[5];
  const float* gcn_W      = (const float*)d_in[6];
  const float* gcn_b      = (const float*)d_in[7];
  const float* gat_W      = (const float*)d_in[8];
  const float* gat_b      = (const float*)d_in[9];
  const float* attn_W     = (const float*)d_in[10];
  const float* attn_b     = (const float*)d_in[11];
  const float* fuse_W     = (const float*)d_in[12];
  const float* fuse_b     = (const float*)d_in[13];
  const float* actor_W    = (const float*)d_in[14];
  const float* actor_b    = (const float*)d_in[15];
  const float* cW1        = (const float*)d_in[16];
  const float* cb1        = (const float*)d_in[17];
  const float* cW2        = (const float*)d_in[18];
  const float* cb2        = (const float*)d_in[19];
  const float* layer_w    = (const float*)d_in[20];

  const int ND = NTOT * D;            // 524288
  float* ws      = (float*)d_ws;
  float* all_emb = ws;
  float* gcn1    = all_emb + ND;
  float* gcn2    = gcn1 + ND;
  float* gat1    = gcn2 + ND;
  float* gat2    = gat1 + ND;
  float* hbuf    = gat2 + ND;
  float* fusedb  = hbuf + ND;
  float* qv      = fusedb + ND;       // 8192
  float* kv      = qv + NTOT;         // 8192
  float* Spart   = kv + NTOT;         // 16384
  float* Svec    = Spart + 256*D;     // 64
  int*   nnz     = (int*)(Svec + D);  // 8192
  int*   ell     = nnz + NTOT;        // 8192*128

  build_ell<<<NTOT/4, 256, 0, stream>>>(adj, ell, nnz);
  concat_emb<<<ND/256, 256, 0, stream>>>(user_table, item_table, all_emb);

  // GCN branch
  gcn_layer<<<NTOT/4, 256, 0, stream>>>(all_emb, ell, nnz, gcn_W,        gcn_b,     gcn1);
  gcn_layer<<<NTOT/4, 256, 0, stream>>>(gcn1,    ell, nnz, gcn_W + D*D,  gcn_b + D, gcn2);

  // GAT layer 0
  gat_h<<<NTOT/4, 256, 0, stream>>>(all_emb, gat_W, gat_b, attn_W, hbuf, qv, kv);
  colsum_part<<<256, 64, 0, stream>>>(hbuf, Spart);
  colsum_final<<<1, 64, 0, stream>>>(Spart, Svec);
  gat_attn<<<NTOT/4, 256, 0, stream>>>(hbuf, qv, kv, ell, nnz, Svec, attn_b, gat1);

  // GAT layer 1
  gat_h<<<NTOT/4, 256, 0, stream>>>(gat1, gat_W + D*D, gat_b + D, attn_W + 2*D, hbuf, qv, kv);
  colsum_part<<<256, 64, 0, stream>>>(hbuf, Spart);
  colsum_final<<<1, 64, 0, stream>>>(Spart, Svec);
  gat_attn<<<NTOT/4, 256, 0, stream>>>(hbuf, qv, kv, ell, nnz, Svec, attn_b + 1, gat2);

  fuse_kernel<<<NTOT/4, 256, 0, stream>>>(gcn1, gat1, gcn2, gat2, fuse_W, fuse_b, layer_w, fusedb);
  score_kernel<<<4096/4, 256, 0, stream>>>(fusedb, users, pos, neg,
                                           actor_W, actor_b, cW1, cb1, cW2, cb2,
                                           (float*)d_out);
}